// Round 9
// baseline (353.296 us; speedup 1.0000x reference)
//
#include <hip/hip_runtime.h>

// ---------------------------------------------------------------------------
// SchNet-style GNN on MI355X — R25.
// R24 (335.6us): all kernels below the 43us fill floor; ~135us of the total
// is graph structure (13 serial dispatches, aggb round-trip, k_s2's 196
// blocks serialized behind independent work). R25 restructures the graph:
//  - k_pre: wtab + prep + gcur/out zeroing in ONE dispatch (blockIdx branch)
//  - k_s2n0: s2 (196 blocks) + node0 (782 blocks) in ONE dispatch (overlap)
//  - k_eu / k_ef: k_edge fused into k_update / k_final. Wave w's phase-1
//    (R24 8-lane-group gather MLP, 16 nodes serial) writes bf16 straight
//    into its LDS arena in staged layout; phase-2 MFMA unchanged. No aggb.
//    xjb ping-pong (xjb0/xjb1) since fused blocks write xjb while others
//    still gather it. 13 dispatches -> 6. Math bit-identical to R24.
// ---------------------------------------------------------------------------

typedef short bf16x8 __attribute__((ext_vector_type(8)));
typedef unsigned short ushort8 __attribute__((ext_vector_type(8)));
typedef float floatx4 __attribute__((ext_vector_type(4)));

#define HCH 128
#define FCH 64
#define GCH 50
#define LN  3
#define TBL 4096
#define CAP2 12288       // slots per 256-node coarse bucket (mean 8192, sigma~90)
#define CHUNK 4096       // edges per k_s1 block (16/thread)
#define DMAX 8.6603f     // pos in [0,5)^3 -> d <= 5*sqrt(3)

#define MFMA(a, b, c) __builtin_amdgcn_mfma_f32_16x16x32_bf16((a), (b), (c), 0, 0, 0)

__device__ __forceinline__ unsigned short f2bf(float x) {
    unsigned int u = __float_as_uint(x);
    unsigned int r = (u + 0x7FFFu + ((u >> 16) & 1u)) >> 16;
    return (unsigned short)r;
}

__device__ __forceinline__ unsigned pk2bf(float lo, float hi) {
    unsigned ulo = __float_as_uint(lo) + 0x8000u;
    unsigned uhi = __float_as_uint(hi) + 0x8000u;
    return __builtin_amdgcn_perm(uhi, ulo, 0x07060302u);
}

__device__ __forceinline__ float bf2f(unsigned short u) {
    return __uint_as_float((unsigned)u << 16);
}

__device__ __forceinline__ float sspf(float x) {
    float t = __expf(-fabsf(x));
    float l = __logf(1.f + t);
    return fmaxf(x, 0.f) + l - 0.69314718056f;
}

__device__ __forceinline__ void fill_frag(const float* __restrict__ src,
                                          short* __restrict__ dst,
                                          int K, int F, int Ksrc,
                                          int tid, int nthr)
{
    int kc = K >> 5;
    int total = (F >> 4) * kc * 512;
    for (int i = tid; i < total; i += nthr) {
        int j = i & 7;
        int lane = (i >> 3) & 63;
        int rest = i >> 9;
        int kk = rest % kc;
        int nt = rest / kc;
        int k = kk * 32 + ((lane >> 4) << 3) + j;
        int f = nt * 16 + (lane & 15);
        float v = (k < Ksrc) ? src[k * F + f] : 0.f;
        dst[i] = (short)f2bf(v);
    }
}

// ---------------------------------------------------------------------------
// k_pre: one dispatch for all independent prologue work.
//   blocks [0, LN*TBL)        : Wtab
//   blocks [LN*TBL, +32)      : weight frag prep
//   block  LN*TBL+32          : zero gcur + out
// ---------------------------------------------------------------------------
__global__ __launch_bounds__(64) void k_pre(
    const float* __restrict__ mw1, const float* __restrict__ mb1,
    const float* __restrict__ mw2, const float* __restrict__ mb2,
    unsigned short* __restrict__ Wtb,
    const float* __restrict__ l1w, const float* __restrict__ l2w,
    const float* __restrict__ lw,  const float* __restrict__ ow1,
    short* __restrict__ l1wp, short* __restrict__ l2wp,
    short* __restrict__ lwp,  short* __restrict__ ow1p,
    int* __restrict__ gcur, float* __restrict__ out, int nb2, int osz)
{
    __shared__ float sh[64];
    int blk = blockIdx.x;
    int f = threadIdx.x;
    if (blk < LN * TBL) {
        int l = blk / TBL, k = blk - l * TBL;
        float d = (float)k * (DMAX / (float)(TBL - 1));
        const float step = 10.f / 49.f;
        const float coeff = -0.5f / (step * step);
        float t1 = mb1[l * 64 + f];
        const float* w1 = mw1 + l * GCH * 64;
        for (int g = 0; g < GCH; g++) {
            float u = d - (float)g * step;
            t1 += __expf(coeff * u * u) * w1[g * 64 + f];
        }
        sh[f] = sspf(t1);              // one wave: program order suffices
        float acc = mb2[l * 64 + f];
        const float* w2 = mw2 + l * 64 * 64;
        for (int g = 0; g < 64; g++) acc += sh[g] * w2[g * 64 + f];
        float C = 0.5f * (__cosf(d * 0.31415926535897932f) + 1.f);
        Wtb[(size_t)blk * 64 + f] = f2bf(acc * C);
    } else if (blk < LN * TBL + 32) {
        int tid = (blk - LN * TBL) * 64 + f;
        int nthr = 32 * 64;
        for (int l = 0; l < LN; l++) {
            fill_frag(l1w + l * HCH * FCH, l1wp + l * 8192, 128, 64, 128, tid, nthr);
            fill_frag(l2w + l * FCH * HCH, l2wp + l * 8192, 64, 128, 64, tid, nthr);
            fill_frag(lw  + l * HCH * HCH, lwp  + l * 16384, 128, 128, 128, tid, nthr);
        }
        fill_frag(ow1, ow1p, 128, 64, 128, tid, nthr);
    } else {
        for (int i = f; i < nb2 * 16; i += 64) gcur[i] = 0;
        for (int i = f; i < osz; i += 64) out[i] = 0.f;
    }
}

// ---------------------------------------------------------------------------
// Stage 1: coarse-bucket (dst>>8) partition of a 4096-edge chunk. (unchanged)
// ---------------------------------------------------------------------------
__global__ __launch_bounds__(256) void k_s1(
    const int* __restrict__ ei, const float* __restrict__ pos,
    int* __restrict__ gcur, int2* __restrict__ ebuf, int E, int nb2)
{
    __shared__ int hist[256];
    __shared__ int lstart[256];
    __shared__ int lcur[256];
    __shared__ int gbase[256];
    __shared__ int wsum[4];
    __shared__ int2 stage[CHUNK];

    int t = threadIdx.x, lane = t & 63, w = t >> 6;
    int e0 = blockIdx.x * CHUNK;
    int e1 = min(e0 + CHUNK, E);
    int cnt = e1 - e0;

    hist[t] = 0;
    __syncthreads();

    int2 my[16];
    int  mybk[16];
#pragma unroll
    for (int i = 0; i < 16; i++) {
        int e = e0 + t + i * 256;
        int ec = min(e, E - 1);
        int s = ei[ec];
        int d2 = ei[E + ec];
        float dx = pos[s * 3 + 0] - pos[d2 * 3 + 0];
        float dy = pos[s * 3 + 1] - pos[d2 * 3 + 1];
        float dz = pos[s * 3 + 2] - pos[d2 * 3 + 2];
        float dist = sqrtf(dx * dx + dy * dy + dz * dz);
        int tix = (int)(dist * ((float)(TBL - 1) / DMAX) + 0.5f);
        tix = (tix > TBL - 1) ? (TBL - 1) : tix;
        my[i] = make_int2(s | (tix << 17), d2);
        mybk[i] = (e < e1) ? (d2 >> 8) : -1;
        if (mybk[i] >= 0) atomicAdd(&hist[mybk[i]], 1);
    }
    __syncthreads();

    int base0;
    {
        int c = hist[t];
        int a = c;
#pragma unroll
        for (int o = 1; o < 64; o <<= 1) {
            int u = __shfl_up(a, o, 64);
            if (lane >= o) a += u;
        }
        if (lane == 63) wsum[w] = a;
        __syncthreads();
        int prefix = 0;
#pragma unroll
        for (int i = 0; i < 4; i++) if (i < w) prefix += wsum[i];
        int ls = prefix + a - c;
        lstart[t] = ls; lcur[t] = ls;
        base0 = (c && t < nb2) ? atomicAdd(&gcur[t * 16], c) : 0;
    }
    __syncthreads();

#pragma unroll
    for (int i = 0; i < 16; i++) {
        if (mybk[i] >= 0) {
            int ofs = atomicAdd(&lcur[mybk[i]], 1);
            stage[ofs] = my[i];
        }
    }
    gbase[t] = t * CAP2 + base0;
    __syncthreads();

    for (int i = t; i < cnt; i += 256) {
        int2 ed = stage[i];
        int bk = ed.y >> 8;
        int g = gbase[bk] + (i - lstart[bk]);
        if (g < bk * CAP2 + CAP2) ebuf[g] = ed;
    }
}

// ---------------------------------------------------------------------------
// k_s2n0: one dispatch. blocks [0,nb2): per-bucket counting sort + rowptr;
// blocks [nb2, nb2+NB): node0 (h = emb[z]; xjb0 = h @ l1w[0]) on t<256.
// The two halves are independent; merging lets them overlap on the GPU.
// ---------------------------------------------------------------------------
__global__ __launch_bounds__(512) void k_s2n0(
    const int2* __restrict__ ebuf, const int* __restrict__ gcur,
    int2* __restrict__ edata, int* __restrict__ rowptr, int nb2,
    const int* __restrict__ z, const float* __restrict__ emb,
    const short* __restrict__ l1wp0, float* __restrict__ h,
    unsigned short* __restrict__ xjb, int N)
{
    __shared__ int hist[256];
    __shared__ int bcur[256];
    __shared__ int wred[8];
    __shared__ __align__(16) short A3[8192];
    __shared__ int zL[64];
    int t = threadIdx.x, lane = t & 63, w = t >> 6;
    int bk = blockIdx.x;
    if (bk < nb2) {
        int cnt = min(gcur[bk * 16], CAP2);
        int v = (t < bk && t < nb2) ? min(gcur[t * 16], CAP2) : 0;
#pragma unroll
        for (int o = 32; o; o >>= 1) v += __shfl_down(v, o, 64);
        if (lane == 0) wred[w] = v;
        if (t < 256) hist[t] = 0;
        __syncthreads();
        int gs = 0;
#pragma unroll
        for (int i = 0; i < 8; i++) gs += wred[i];

        const int2* eb = ebuf + (size_t)bk * CAP2;
        for (int i = t; i < cnt; i += 512)
            atomicAdd(&hist[eb[i].y & 255], 1);
        __syncthreads();
        int myc = (t < 256) ? hist[t] : 0;
        for (int o = 1; o < 256; o <<= 1) {
            int u = (t < 256 && t >= o) ? hist[t - o] : 0;
            __syncthreads();
            if (t < 256) hist[t] += u;
            __syncthreads();
        }
        if (t < 256) {
            int start = gs + hist[t] - myc;
            bcur[t] = start;
            rowptr[(bk << 8) + t] = start;
        }
        if (bk == nb2 - 1 && t == 0) rowptr[nb2 << 8] = gs + cnt;
        __syncthreads();
        for (int i = t; i < cnt; i += 512) {
            int2 ed = eb[i];
            int dl = ed.y & 255;
            int p = atomicAdd(&bcur[dl], 1);
            edata[p] = ed;
        }
    } else {
        int n0 = (bk - nb2) * 64;
        if (t < 64) { int n = n0 + t; zL[t] = (n < N) ? z[n] : 0; }
        __syncthreads();
        if (t < 256) {
#pragma unroll
            for (int m = 0; m < 16; m++) {
                int ii = lane + 64 * m;
                int rloc = ii >> 6;
                int k0 = (ii & 63) * 2;
                int n = n0 + w * 16 + rloc;
                float2 v = make_float2(0.f, 0.f);
                if (n < N) {
                    v = *(const float2*)(&emb[(size_t)zL[w * 16 + rloc] * HCH + k0]);
                    *(float2*)(&h[(size_t)n * HCH + k0]) = v;
                }
                unsigned pk = pk2bf(v.x, v.y);
                int si = w * 2048 + (k0 >> 5) * 512 + (rloc + 16 * ((k0 >> 3) & 3)) * 8 + (k0 & 7);
                *(unsigned*)(&A3[si]) = pk;
            }
            int quad = lane >> 4, col = lane & 15;
            const bf16x8* B = (const bf16x8*)l1wp0;
            bf16x8 af[4];
#pragma unroll
            for (int kk = 0; kk < 4; kk++)
                af[kk] = *(const bf16x8*)(&A3[w * 2048 + kk * 512 + lane * 8]);
#pragma unroll
            for (int nt = 0; nt < 4; nt++) {
                floatx4 c = {0.f, 0.f, 0.f, 0.f};
#pragma unroll
                for (int kk = 0; kk < 4; kk++) c = MFMA(af[kk], B[(nt * 4 + kk) * 64 + lane], c);
                int f = nt * 16 + col;
#pragma unroll
                for (int reg = 0; reg < 4; reg++) {
                    int n = n0 + w * 16 + quad * 4 + reg;
                    if (n < N) xjb[(size_t)n * FCH + f] = f2bf(c[reg]);
                }
            }
        }
    }
}

// ---------------------------------------------------------------------------
// Phase-1 edge aggregation for one wave's 16 nodes -> bf16 into WR arena
// in the staged si layout (identical values to R24's aggb path).
// ---------------------------------------------------------------------------
__device__ __forceinline__ void edge_phase(
    const int* __restrict__ rowptr, const int2* __restrict__ edata,
    const unsigned short* __restrict__ xin, const unsigned short* __restrict__ Wt,
    short* __restrict__ WR, int nbase, int lane)
{
    int slot = lane >> 3;
    int cq = (lane & 7) * 8;
    const unsigned short* xp = xin + cq;
    const unsigned short* wp = Wt + cq;
    int rp = (lane < 17) ? rowptr[nbase + lane] : 0;
    for (int i = 0; i < 16; i++) {
        int beg = __shfl(rp, i, 64);
        int end = __shfl(rp, i + 1, 64);
        float acc[8];
#pragma unroll
        for (int j = 0; j < 8; j++) acc[j] = 0.f;
        for (int e = beg; e < end; e += 16) {
            int eb = e + slot * 2;
            int2 ed0 = edata[min(eb + 0, end - 1)];
            int2 ed1 = edata[min(eb + 1, end - 1)];
            int exv[2] = {ed0.x, ed1.x};
            uint4 xq[2], wq[2];
#pragma unroll
            for (int k = 0; k < 2; k++) {
                int s   = exv[k] & 0x1FFFF;
                int tix = (int)(((unsigned)exv[k]) >> 17);
                xq[k] = *(const uint4*)(xp + ((size_t)s << 6));
                wq[k] = *(const uint4*)(wp + ((size_t)tix << 6));
            }
#pragma unroll
            for (int k = 0; k < 2; k++) {
                if (eb + k >= end) { wq[k].x = 0u; wq[k].y = 0u; wq[k].z = 0u; wq[k].w = 0u; }
                acc[0] += __uint_as_float(xq[k].x << 16)         * __uint_as_float(wq[k].x << 16);
                acc[1] += __uint_as_float(xq[k].x & 0xFFFF0000u) * __uint_as_float(wq[k].x & 0xFFFF0000u);
                acc[2] += __uint_as_float(xq[k].y << 16)         * __uint_as_float(wq[k].y << 16);
                acc[3] += __uint_as_float(xq[k].y & 0xFFFF0000u) * __uint_as_float(wq[k].y & 0xFFFF0000u);
                acc[4] += __uint_as_float(xq[k].z << 16)         * __uint_as_float(wq[k].z << 16);
                acc[5] += __uint_as_float(xq[k].z & 0xFFFF0000u) * __uint_as_float(wq[k].z & 0xFFFF0000u);
                acc[6] += __uint_as_float(xq[k].w << 16)         * __uint_as_float(wq[k].w << 16);
                acc[7] += __uint_as_float(xq[k].w & 0xFFFF0000u) * __uint_as_float(wq[k].w & 0xFFFF0000u);
            }
        }
#pragma unroll
        for (int o = 8; o < 64; o <<= 1) {
#pragma unroll
            for (int j = 0; j < 8; j++) acc[j] += __shfl_xor(acc[j], o, 64);
        }
        if (slot == 0) {
#pragma unroll
            for (int j = 0; j < 4; j++) {
                int k0 = cq + 2 * j;
                int si = (k0 >> 5) * 512 + (i + 16 * ((k0 >> 3) & 3)) * 8 + (k0 & 7);
                *(unsigned*)(&WR[si]) = pk2bf(acc[2 * j], acc[2 * j + 1]);
            }
        }
    }
}

// ---------------------------------------------------------------------------
// k_eu: fused edge + node-update (layers 0,1). Wave-local: phase-1 fills the
// wave's WR arena, phase-2 MFMA consumes it. No barrier, no aggb.
// Reads xin (prev layer's xj), writes xout (next layer's xj) + h.
// ---------------------------------------------------------------------------
__global__ __launch_bounds__(256) void k_eu(
    const int* __restrict__ rowptr, const int2* __restrict__ edata,
    const unsigned short* __restrict__ xin, const unsigned short* __restrict__ Wt,
    const short* __restrict__ l2wp, const float* __restrict__ l2b,
    const short* __restrict__ lwp,  const float* __restrict__ lb,
    const short* __restrict__ l1wp_next,
    float* __restrict__ h, unsigned short* __restrict__ xout, int layer, int N)
{
    __shared__ __align__(16) short AR[8192];
    int t = threadIdx.x, lane = t & 63, w = t >> 6;
    int n0 = blockIdx.x * 64;
    short* WR = &AR[w * 2048];

    edge_phase(rowptr, edata, xin, Wt, WR, n0 + w * 16, lane);

    int quad = lane >> 4, col = lane & 15;
    const bf16x8* Bl2 = (const bf16x8*)(l2wp + layer * 8192);
    const bf16x8* Blw = (const bf16x8*)(lwp + layer * 16384);
    const bf16x8* Bl1 = (const bf16x8*)l1wp_next;

    bf16x8 a0 = *(const bf16x8*)(&WR[lane * 8]);
    bf16x8 a1 = *(const bf16x8*)(&WR[512 + lane * 8]);
#pragma unroll
    for (int nt = 0; nt < 8; nt++) {
        float bias = l2b[layer * HCH + nt * 16 + col];
        floatx4 c = {bias, bias, bias, bias};
        c = MFMA(a0, Bl2[(nt * 2 + 0) * 64 + lane], c);
        c = MFMA(a1, Bl2[(nt * 2 + 1) * 64 + lane], c);
        int f = nt * 16 + col;
        int si0 = (f >> 5) * 512 + (16 * ((f >> 3) & 3)) * 8 + (f & 7);
#pragma unroll
        for (int reg = 0; reg < 4; reg++)
            WR[si0 + (quad * 4 + reg) * 8] = (short)f2bf(sspf(c[reg]));
    }
    bf16x8 af[4];
#pragma unroll
    for (int kk = 0; kk < 4; kk++)
        af[kk] = *(const bf16x8*)(&WR[kk * 512 + lane * 8]);
#pragma unroll
    for (int nt = 0; nt < 8; nt++) {
        float bias = lb[layer * HCH + nt * 16 + col];
        floatx4 c = {bias, bias, bias, bias};
#pragma unroll
        for (int kk = 0; kk < 4; kk++) c = MFMA(af[kk], Blw[(nt * 4 + kk) * 64 + lane], c);
        int f = nt * 16 + col;
        int si0 = (f >> 5) * 512 + (16 * ((f >> 3) & 3)) * 8 + (f & 7);
#pragma unroll
        for (int reg = 0; reg < 4; reg++) {
            int n = n0 + w * 16 + quad * 4 + reg;
            float hv = 0.f;
            if (n < N) {
                hv = h[(size_t)n * HCH + f] + c[reg];
                h[(size_t)n * HCH + f] = hv;
            }
            WR[si0 + (quad * 4 + reg) * 8] = (short)f2bf(hv);
        }
    }
#pragma unroll
    for (int kk = 0; kk < 4; kk++)
        af[kk] = *(const bf16x8*)(&WR[kk * 512 + lane * 8]);
#pragma unroll
    for (int nt = 0; nt < 4; nt++) {
        floatx4 c = {0.f, 0.f, 0.f, 0.f};
#pragma unroll
        for (int kk = 0; kk < 4; kk++) c = MFMA(af[kk], Bl1[(nt * 4 + kk) * 64 + lane], c);
        int f = nt * 16 + col;
#pragma unroll
        for (int reg = 0; reg < 4; reg++) {
            int n = n0 + w * 16 + quad * 4 + reg;
            if (n < N) xout[(size_t)n * FCH + f] = f2bf(c[reg]);
        }
    }
}

// ---------------------------------------------------------------------------
// k_ef: fused edge + final layer (node update + output MLP + readout).
// ---------------------------------------------------------------------------
__global__ __launch_bounds__(256) void k_ef(
    const int* __restrict__ rowptr, const int2* __restrict__ edata,
    const unsigned short* __restrict__ xin, const unsigned short* __restrict__ Wt,
    const short* __restrict__ l2wp, const float* __restrict__ l2b,
    const short* __restrict__ lwp,  const float* __restrict__ lb,
    const short* __restrict__ ow1p, const float* __restrict__ ob1,
    const float* __restrict__ ow2,  const float* __restrict__ ob2,
    const int* __restrict__ batch,  const float* __restrict__ h,
    float* __restrict__ out, int layer, int N)
{
    __shared__ __align__(16) short AR[8192];
    __shared__ float R[64 * 17];
    int t = threadIdx.x, lane = t & 63, w = t >> 6;
    int n0 = blockIdx.x * 64;
    short* WR = &AR[w * 2048];

    edge_phase(rowptr, edata, xin, Wt, WR, n0 + w * 16, lane);

    int quad = lane >> 4, col = lane & 15;
    const bf16x8* Bl2 = (const bf16x8*)(l2wp + layer * 8192);
    const bf16x8* Blw = (const bf16x8*)(lwp + layer * 16384);
    const bf16x8* Bow = (const bf16x8*)ow1p;

    bf16x8 a0 = *(const bf16x8*)(&WR[lane * 8]);
    bf16x8 a1 = *(const bf16x8*)(&WR[512 + lane * 8]);
#pragma unroll
    for (int nt = 0; nt < 8; nt++) {
        float bias = l2b[layer * HCH + nt * 16 + col];
        floatx4 c = {bias, bias, bias, bias};
        c = MFMA(a0, Bl2[(nt * 2 + 0) * 64 + lane], c);
        c = MFMA(a1, Bl2[(nt * 2 + 1) * 64 + lane], c);
        int f = nt * 16 + col;
        int si0 = (f >> 5) * 512 + (16 * ((f >> 3) & 3)) * 8 + (f & 7);
#pragma unroll
        for (int reg = 0; reg < 4; reg++)
            WR[si0 + (quad * 4 + reg) * 8] = (short)f2bf(sspf(c[reg]));
    }
    bf16x8 af[4];
#pragma unroll
    for (int kk = 0; kk < 4; kk++)
        af[kk] = *(const bf16x8*)(&WR[kk * 512 + lane * 8]);
#pragma unroll
    for (int nt = 0; nt < 8; nt++) {
        float bias = lb[layer * HCH + nt * 16 + col];
        floatx4 c = {bias, bias, bias, bias};
#pragma unroll
        for (int kk = 0; kk < 4; kk++) c = MFMA(af[kk], Blw[(nt * 4 + kk) * 64 + lane], c);
        int f = nt * 16 + col;
        int si0 = (f >> 5) * 512 + (16 * ((f >> 3) & 3)) * 8 + (f & 7);
#pragma unroll
        for (int reg = 0; reg < 4; reg++) {
            int n = n0 + w * 16 + quad * 4 + reg;
            float hv = 0.f;
            if (n < N) hv = h[(size_t)n * HCH + f] + c[reg];
            WR[si0 + (quad * 4 + reg) * 8] = (short)f2bf(hv);
        }
    }
#pragma unroll
    for (int kk = 0; kk < 4; kk++)
        af[kk] = *(const bf16x8*)(&WR[kk * 512 + lane * 8]);
    float p[4] = {0.f, 0.f, 0.f, 0.f};
#pragma unroll
    for (int nt = 0; nt < 4; nt++) {
        float bias = ob1[nt * 16 + col];
        floatx4 c = {bias, bias, bias, bias};
#pragma unroll
        for (int kk = 0; kk < 4; kk++) c = MFMA(af[kk], Bow[(nt * 4 + kk) * 64 + lane], c);
        float w2 = ow2[nt * 16 + col];
#pragma unroll
        for (int reg = 0; reg < 4; reg++) p[reg] += sspf(c[reg]) * w2;
    }
#pragma unroll
    for (int reg = 0; reg < 4; reg++)
        R[(w * 16 + quad * 4 + reg) * 17 + col] = p[reg];
    __syncthreads();
    if (t < 64) {
        int n = n0 + t;
        float v = 0.f;
        int g = -1;
        if (n < N) {
            v = ob2[0];
#pragma unroll
            for (int c2 = 0; c2 < 16; c2++) v += R[t * 17 + c2];
            g = batch[n];
        }
#pragma unroll
        for (int off2 = 1; off2 < 64; off2 <<= 1) {
            float vv = __shfl_down(v, off2, 64);
            int gg = __shfl_down(g, off2, 64);
            if (lane + off2 < 64 && gg == g) v += vv;
        }
        int gp = __shfl_up(g, 1, 64);
        bool head = (lane == 0) || (g != gp);
        if (head && g >= 0) unsafeAtomicAdd(&out[g], v);
    }
}

// ---------------------------------------------------------------------------
extern "C" void kernel_launch(void* const* d_in, const int* in_sizes, int n_in,
                              void* d_out, int out_size, void* d_ws, size_t ws_size,
                              hipStream_t stream)
{
    const int*   z    = (const int*)d_in[0];
    const float* pos  = (const float*)d_in[1];
    const int*   batc = (const int*)d_in[2];
    const int*   ei   = (const int*)d_in[3];
    const float* emb  = (const float*)d_in[4];
    const float* mw1  = (const float*)d_in[5];
    const float* mb1  = (const float*)d_in[6];
    const float* mw2  = (const float*)d_in[7];
    const float* mb2  = (const float*)d_in[8];
    const float* l1w  = (const float*)d_in[9];
    const float* l2w  = (const float*)d_in[10];
    const float* l2b  = (const float*)d_in[11];
    const float* lw   = (const float*)d_in[12];
    const float* lb   = (const float*)d_in[13];
    const float* ow1  = (const float*)d_in[14];
    const float* ob1  = (const float*)d_in[15];
    const float* ow2  = (const float*)d_in[16];
    const float* ob2  = (const float*)d_in[17];
    float* out = (float*)d_out;

    int N = in_sizes[0];
    int E = in_sizes[3] / 2;
    int nb2 = (N + 255) >> 8;        // coarse buckets (<=256 for N<=65536)

    char* ws = (char*)d_ws;
    size_t off = 0;
    auto alloc = [&](size_t bytes) {
        void* p = ws + off;
        off = (off + bytes + 255) & ~(size_t)255;
        return p;
    };
    float* h      = (float*)alloc((size_t)N * HCH * 4);
    unsigned short* xjb0 = (unsigned short*)alloc((size_t)N * FCH * 2);
    unsigned short* xjb1 = (unsigned short*)alloc((size_t)N * FCH * 2);
    int2*  ebuf   = (int2*)alloc((size_t)nb2 * CAP2 * 8);
    int2*  edata  = (int2*)alloc((size_t)E * 8);
    unsigned short* Wtab = (unsigned short*)alloc((size_t)LN * TBL * 64 * 2);
    int*   gcur   = (int*)alloc((size_t)nb2 * 64);      // 1 cursor / 64B line
    int*   rowptr = (int*)alloc(((size_t)nb2 * 256 + 1) * 4);
    short* l1wp   = (short*)alloc(LN * 8192 * 2);
    short* l2wp   = (short*)alloc(LN * 8192 * 2);
    short* lwp    = (short*)alloc(LN * 16384 * 2);
    short* ow1p   = (short*)alloc(8192 * 2);

    int NB = (N + 63) / 64;
    int S1B = (E + CHUNK - 1) / CHUNK;
    int PREB = LN * TBL + 32 + 1;

    k_pre<<<PREB, 64, 0, stream>>>(mw1, mb1, mw2, mb2, Wtab,
                                   l1w, l2w, lw, ow1, l1wp, l2wp, lwp, ow1p,
                                   gcur, out, nb2, out_size);
    k_s1<<<S1B, 256, 0, stream>>>(ei, pos, gcur, ebuf, E, nb2);
    k_s2n0<<<nb2 + NB, 512, 0, stream>>>(ebuf, gcur, edata, rowptr, nb2,
                                         z, emb, l1wp, h, xjb0, N);
    k_eu<<<NB, 256, 0, stream>>>(rowptr, edata, xjb0, Wtab,
                                 l2wp, l2b, lwp, lb, l1wp + 8192,
                                 h, xjb1, 0, N);
    k_eu<<<NB, 256, 0, stream>>>(rowptr, edata, xjb1, Wtab + (size_t)TBL * 64,
                                 l2wp, l2b, lwp, lb, l1wp + 2 * 8192,
                                 h, xjb0, 1, N);
    k_ef<<<NB, 256, 0, stream>>>(rowptr, edata, xjb0, Wtab + (size_t)2 * TBL * 64,
                                 l2wp, l2b, lwp, lb, ow1p, ob1, ow2, ob2,
                                 batc, h, out, 2, N);
}

// Round 10
// 330.408 us; speedup vs baseline: 1.0693x; 1.0693x over previous
//
#include <hip/hip_runtime.h>

// ---------------------------------------------------------------------------
// SchNet-style GNN on MI355X — R26.
// R25 (353.3us) fused edge into update (k_eu) and lost: 3128 waves x 16
// serial nodes vs R24's 50000 independent waves -> occ 28%, 69.7us. The
// edge phase lives on wave count (R21 lesson, re-confirmed). R26 keeps
// R25's good merges (k_pre: wtab+prep+zeroing; k_s2n0: s2 overlapped with
// node0) and reverts the edge path to R24 exactly: standalone k_edge
// (1 wave/node, uint4 gathers, bf16 aggb) + k_update/k_final.
// 13 (R24) -> 9 dispatches with R24's per-kernel performance.
// ---------------------------------------------------------------------------

typedef short bf16x8 __attribute__((ext_vector_type(8)));
typedef unsigned short ushort8 __attribute__((ext_vector_type(8)));
typedef float floatx4 __attribute__((ext_vector_type(4)));

#define HCH 128
#define FCH 64
#define GCH 50
#define LN  3
#define TBL 4096
#define CAP2 12288       // slots per 256-node coarse bucket (mean 8192, sigma~90)
#define CHUNK 4096       // edges per k_s1 block (16/thread)
#define DMAX 8.6603f     // pos in [0,5)^3 -> d <= 5*sqrt(3)

#define MFMA(a, b, c) __builtin_amdgcn_mfma_f32_16x16x32_bf16((a), (b), (c), 0, 0, 0)

__device__ __forceinline__ unsigned short f2bf(float x) {
    unsigned int u = __float_as_uint(x);
    unsigned int r = (u + 0x7FFFu + ((u >> 16) & 1u)) >> 16;
    return (unsigned short)r;
}

__device__ __forceinline__ unsigned pk2bf(float lo, float hi) {
    unsigned ulo = __float_as_uint(lo) + 0x8000u;
    unsigned uhi = __float_as_uint(hi) + 0x8000u;
    return __builtin_amdgcn_perm(uhi, ulo, 0x07060302u);
}

__device__ __forceinline__ float bf2f(unsigned short u) {
    return __uint_as_float((unsigned)u << 16);
}

__device__ __forceinline__ float sspf(float x) {
    float t = __expf(-fabsf(x));
    float l = __logf(1.f + t);
    return fmaxf(x, 0.f) + l - 0.69314718056f;
}

__device__ __forceinline__ void fill_frag(const float* __restrict__ src,
                                          short* __restrict__ dst,
                                          int K, int F, int Ksrc,
                                          int tid, int nthr)
{
    int kc = K >> 5;
    int total = (F >> 4) * kc * 512;
    for (int i = tid; i < total; i += nthr) {
        int j = i & 7;
        int lane = (i >> 3) & 63;
        int rest = i >> 9;
        int kk = rest % kc;
        int nt = rest / kc;
        int k = kk * 32 + ((lane >> 4) << 3) + j;
        int f = nt * 16 + (lane & 15);
        float v = (k < Ksrc) ? src[k * F + f] : 0.f;
        dst[i] = (short)f2bf(v);
    }
}

// ---------------------------------------------------------------------------
// k_pre: one dispatch for all independent prologue work.
//   blocks [0, LN*TBL)        : Wtab
//   blocks [LN*TBL, +32)      : weight frag prep
//   block  LN*TBL+32          : zero gcur + out
// ---------------------------------------------------------------------------
__global__ __launch_bounds__(64) void k_pre(
    const float* __restrict__ mw1, const float* __restrict__ mb1,
    const float* __restrict__ mw2, const float* __restrict__ mb2,
    unsigned short* __restrict__ Wtb,
    const float* __restrict__ l1w, const float* __restrict__ l2w,
    const float* __restrict__ lw,  const float* __restrict__ ow1,
    short* __restrict__ l1wp, short* __restrict__ l2wp,
    short* __restrict__ lwp,  short* __restrict__ ow1p,
    int* __restrict__ gcur, float* __restrict__ out, int nb2, int osz)
{
    __shared__ float sh[64];
    int blk = blockIdx.x;
    int f = threadIdx.x;
    if (blk < LN * TBL) {
        int l = blk / TBL, k = blk - l * TBL;
        float d = (float)k * (DMAX / (float)(TBL - 1));
        const float step = 10.f / 49.f;
        const float coeff = -0.5f / (step * step);
        float t1 = mb1[l * 64 + f];
        const float* w1 = mw1 + l * GCH * 64;
        for (int g = 0; g < GCH; g++) {
            float u = d - (float)g * step;
            t1 += __expf(coeff * u * u) * w1[g * 64 + f];
        }
        sh[f] = sspf(t1);              // one wave: program order suffices
        float acc = mb2[l * 64 + f];
        const float* w2 = mw2 + l * 64 * 64;
        for (int g = 0; g < 64; g++) acc += sh[g] * w2[g * 64 + f];
        float C = 0.5f * (__cosf(d * 0.31415926535897932f) + 1.f);
        Wtb[(size_t)blk * 64 + f] = f2bf(acc * C);
    } else if (blk < LN * TBL + 32) {
        int tid = (blk - LN * TBL) * 64 + f;
        int nthr = 32 * 64;
        for (int l = 0; l < LN; l++) {
            fill_frag(l1w + l * HCH * FCH, l1wp + l * 8192, 128, 64, 128, tid, nthr);
            fill_frag(l2w + l * FCH * HCH, l2wp + l * 8192, 64, 128, 64, tid, nthr);
            fill_frag(lw  + l * HCH * HCH, lwp  + l * 16384, 128, 128, 128, tid, nthr);
        }
        fill_frag(ow1, ow1p, 128, 64, 128, tid, nthr);
    } else {
        for (int i = f; i < nb2 * 16; i += 64) gcur[i] = 0;
        for (int i = f; i < osz; i += 64) out[i] = 0.f;
    }
}

// ---------------------------------------------------------------------------
// Stage 1: coarse-bucket (dst>>8) partition of a 4096-edge chunk.
// ---------------------------------------------------------------------------
__global__ __launch_bounds__(256) void k_s1(
    const int* __restrict__ ei, const float* __restrict__ pos,
    int* __restrict__ gcur, int2* __restrict__ ebuf, int E, int nb2)
{
    __shared__ int hist[256];
    __shared__ int lstart[256];
    __shared__ int lcur[256];
    __shared__ int gbase[256];
    __shared__ int wsum[4];
    __shared__ int2 stage[CHUNK];

    int t = threadIdx.x, lane = t & 63, w = t >> 6;
    int e0 = blockIdx.x * CHUNK;
    int e1 = min(e0 + CHUNK, E);
    int cnt = e1 - e0;

    hist[t] = 0;
    __syncthreads();

    int2 my[16];
    int  mybk[16];
#pragma unroll
    for (int i = 0; i < 16; i++) {
        int e = e0 + t + i * 256;
        int ec = min(e, E - 1);
        int s = ei[ec];
        int d2 = ei[E + ec];
        float dx = pos[s * 3 + 0] - pos[d2 * 3 + 0];
        float dy = pos[s * 3 + 1] - pos[d2 * 3 + 1];
        float dz = pos[s * 3 + 2] - pos[d2 * 3 + 2];
        float dist = sqrtf(dx * dx + dy * dy + dz * dz);
        int tix = (int)(dist * ((float)(TBL - 1) / DMAX) + 0.5f);
        tix = (tix > TBL - 1) ? (TBL - 1) : tix;
        my[i] = make_int2(s | (tix << 17), d2);
        mybk[i] = (e < e1) ? (d2 >> 8) : -1;
        if (mybk[i] >= 0) atomicAdd(&hist[mybk[i]], 1);
    }
    __syncthreads();

    int base0;
    {
        int c = hist[t];
        int a = c;
#pragma unroll
        for (int o = 1; o < 64; o <<= 1) {
            int u = __shfl_up(a, o, 64);
            if (lane >= o) a += u;
        }
        if (lane == 63) wsum[w] = a;
        __syncthreads();
        int prefix = 0;
#pragma unroll
        for (int i = 0; i < 4; i++) if (i < w) prefix += wsum[i];
        int ls = prefix + a - c;
        lstart[t] = ls; lcur[t] = ls;
        base0 = (c && t < nb2) ? atomicAdd(&gcur[t * 16], c) : 0;
    }
    __syncthreads();

#pragma unroll
    for (int i = 0; i < 16; i++) {
        if (mybk[i] >= 0) {
            int ofs = atomicAdd(&lcur[mybk[i]], 1);
            stage[ofs] = my[i];
        }
    }
    gbase[t] = t * CAP2 + base0;
    __syncthreads();

    for (int i = t; i < cnt; i += 256) {
        int2 ed = stage[i];
        int bk = ed.y >> 8;
        int g = gbase[bk] + (i - lstart[bk]);
        if (g < bk * CAP2 + CAP2) ebuf[g] = ed;
    }
}

// ---------------------------------------------------------------------------
// k_s2n0: one dispatch. blocks [0,nb2): per-bucket counting sort + rowptr;
// blocks [nb2, nb2+NB): node0 (h = emb[z]; xjb = h @ l1w[0]) on t<256.
// ---------------------------------------------------------------------------
__global__ __launch_bounds__(512) void k_s2n0(
    const int2* __restrict__ ebuf, const int* __restrict__ gcur,
    int2* __restrict__ edata, int* __restrict__ rowptr, int nb2,
    const int* __restrict__ z, const float* __restrict__ emb,
    const short* __restrict__ l1wp0, float* __restrict__ h,
    unsigned short* __restrict__ xjb, int N)
{
    __shared__ int hist[256];
    __shared__ int bcur[256];
    __shared__ int wred[8];
    __shared__ __align__(16) short A3[8192];
    __shared__ int zL[64];
    int t = threadIdx.x, lane = t & 63, w = t >> 6;
    int bk = blockIdx.x;
    if (bk < nb2) {
        int cnt = min(gcur[bk * 16], CAP2);
        int v = (t < bk && t < nb2) ? min(gcur[t * 16], CAP2) : 0;
#pragma unroll
        for (int o = 32; o; o >>= 1) v += __shfl_down(v, o, 64);
        if (lane == 0) wred[w] = v;
        if (t < 256) hist[t] = 0;
        __syncthreads();
        int gs = 0;
#pragma unroll
        for (int i = 0; i < 8; i++) gs += wred[i];

        const int2* eb = ebuf + (size_t)bk * CAP2;
        for (int i = t; i < cnt; i += 512)
            atomicAdd(&hist[eb[i].y & 255], 1);
        __syncthreads();
        int myc = (t < 256) ? hist[t] : 0;
        for (int o = 1; o < 256; o <<= 1) {
            int u = (t < 256 && t >= o) ? hist[t - o] : 0;
            __syncthreads();
            if (t < 256) hist[t] += u;
            __syncthreads();
        }
        if (t < 256) {
            int start = gs + hist[t] - myc;
            bcur[t] = start;
            rowptr[(bk << 8) + t] = start;
        }
        if (bk == nb2 - 1 && t == 0) rowptr[nb2 << 8] = gs + cnt;
        __syncthreads();
        for (int i = t; i < cnt; i += 512) {
            int2 ed = eb[i];
            int dl = ed.y & 255;
            int p = atomicAdd(&bcur[dl], 1);
            edata[p] = ed;
        }
    } else {
        int n0 = (bk - nb2) * 64;
        if (t < 64) { int n = n0 + t; zL[t] = (n < N) ? z[n] : 0; }
        __syncthreads();
        if (t < 256) {
#pragma unroll
            for (int m = 0; m < 16; m++) {
                int ii = lane + 64 * m;
                int rloc = ii >> 6;
                int k0 = (ii & 63) * 2;
                int n = n0 + w * 16 + rloc;
                float2 v = make_float2(0.f, 0.f);
                if (n < N) {
                    v = *(const float2*)(&emb[(size_t)zL[w * 16 + rloc] * HCH + k0]);
                    *(float2*)(&h[(size_t)n * HCH + k0]) = v;
                }
                unsigned pk = pk2bf(v.x, v.y);
                int si = w * 2048 + (k0 >> 5) * 512 + (rloc + 16 * ((k0 >> 3) & 3)) * 8 + (k0 & 7);
                *(unsigned*)(&A3[si]) = pk;
            }
            int quad = lane >> 4, col = lane & 15;
            const bf16x8* B = (const bf16x8*)l1wp0;
            bf16x8 af[4];
#pragma unroll
            for (int kk = 0; kk < 4; kk++)
                af[kk] = *(const bf16x8*)(&A3[w * 2048 + kk * 512 + lane * 8]);
#pragma unroll
            for (int nt = 0; nt < 4; nt++) {
                floatx4 c = {0.f, 0.f, 0.f, 0.f};
#pragma unroll
                for (int kk = 0; kk < 4; kk++) c = MFMA(af[kk], B[(nt * 4 + kk) * 64 + lane], c);
                int f = nt * 16 + col;
#pragma unroll
                for (int reg = 0; reg < 4; reg++) {
                    int n = n0 + w * 16 + quad * 4 + reg;
                    if (n < N) xjb[(size_t)n * FCH + f] = f2bf(c[reg]);
                }
            }
        }
    }
}

// ---------------------------------------------------------------------------
// Edge kernel (R24 structure): one WAVE per dst node, 8-channel lanes via
// uint4. slot = lane>>3 handles 2 edges of each 16-edge batch; lane&7 owns
// an 8-channel group. Output: bf16 agg row. Zero atomics, zero LDS.
// ---------------------------------------------------------------------------
__global__ __launch_bounds__(256) void k_edge(
    const int* __restrict__ rowptr, const int2* __restrict__ edata,
    const unsigned short* __restrict__ xjb, const unsigned short* __restrict__ Wt,
    unsigned short* __restrict__ aggb, int N)
{
    int t = threadIdx.x, lane = t & 63, w = t >> 6;
    int n = blockIdx.x * 4 + w;
    if (n >= N) return;
    int beg = rowptr[n];
    int end = rowptr[n + 1];
    int slot = lane >> 3;            // 0..7: edge pair within the 16-edge batch
    int cq = (lane & 7) * 8;         // 8-channel base
    const unsigned short* xp = xjb + cq;
    const unsigned short* wp = Wt + cq;
    float acc[8];
#pragma unroll
    for (int j = 0; j < 8; j++) acc[j] = 0.f;
    for (int e = beg; e < end; e += 16) {
        int eb = e + slot * 2;
        int2 ed0 = edata[min(eb + 0, end - 1)];
        int2 ed1 = edata[min(eb + 1, end - 1)];
        int exv[2] = {ed0.x, ed1.x};
        uint4 xq[2], wq[2];
#pragma unroll
        for (int i = 0; i < 2; i++) {
            int s   = exv[i] & 0x1FFFF;
            int tix = (int)(((unsigned)exv[i]) >> 17);
            xq[i] = *(const uint4*)(xp + ((size_t)s << 6));
            wq[i] = *(const uint4*)(wp + ((size_t)tix << 6));
        }
#pragma unroll
        for (int i = 0; i < 2; i++) {
            if (eb + i >= end) { wq[i].x = 0u; wq[i].y = 0u; wq[i].z = 0u; wq[i].w = 0u; }
            acc[0] += __uint_as_float(xq[i].x << 16)         * __uint_as_float(wq[i].x << 16);
            acc[1] += __uint_as_float(xq[i].x & 0xFFFF0000u) * __uint_as_float(wq[i].x & 0xFFFF0000u);
            acc[2] += __uint_as_float(xq[i].y << 16)         * __uint_as_float(wq[i].y << 16);
            acc[3] += __uint_as_float(xq[i].y & 0xFFFF0000u) * __uint_as_float(wq[i].y & 0xFFFF0000u);
            acc[4] += __uint_as_float(xq[i].z << 16)         * __uint_as_float(wq[i].z << 16);
            acc[5] += __uint_as_float(xq[i].z & 0xFFFF0000u) * __uint_as_float(wq[i].z & 0xFFFF0000u);
            acc[6] += __uint_as_float(xq[i].w << 16)         * __uint_as_float(wq[i].w << 16);
            acc[7] += __uint_as_float(xq[i].w & 0xFFFF0000u) * __uint_as_float(wq[i].w & 0xFFFF0000u);
        }
    }
#pragma unroll
    for (int o = 8; o < 64; o <<= 1) {
#pragma unroll
        for (int j = 0; j < 8; j++) acc[j] += __shfl_xor(acc[j], o, 64);
    }
    if (slot == 0) {
        uint4 pk;
        pk.x = pk2bf(acc[0], acc[1]);
        pk.y = pk2bf(acc[2], acc[3]);
        pk.z = pk2bf(acc[4], acc[5]);
        pk.w = pk2bf(acc[6], acc[7]);
        *(uint4*)(aggb + (size_t)n * FCH + cq) = pk;
    }
}

// ---------------------------------------------------------------------------
// Node update (layers 0,1): single LDS arena; agg arrives pre-packed bf16.
// ---------------------------------------------------------------------------
__global__ __launch_bounds__(256) void k_update(
    const unsigned short* __restrict__ aggb, const short* __restrict__ l2wp,
    const float* __restrict__ l2b, const short* __restrict__ lwp,
    const float* __restrict__ lb,  const short* __restrict__ l1wp_next,
    float* __restrict__ h, unsigned short* __restrict__ xjb, int layer, int N)
{
    __shared__ __align__(16) short AR[8192];
    int t = threadIdx.x, lane = t & 63, w = t >> 6;
    int n0 = blockIdx.x * 64;
    short* WR = &AR[w * 2048];
#pragma unroll
    for (int m = 0; m < 8; m++) {
        int ii = lane + 64 * m;
        int rloc = ii >> 5;
        int k0 = (ii & 31) * 2;
        int n = n0 + w * 16 + rloc;
        unsigned pk = 0u;
        if (n < N) pk = *(const unsigned*)(&aggb[(size_t)n * FCH + k0]);
        int si = (k0 >> 5) * 512 + (rloc + 16 * ((k0 >> 3) & 3)) * 8 + (k0 & 7);
        *(unsigned*)(&WR[si]) = pk;
    }
    int quad = lane >> 4, col = lane & 15;
    const bf16x8* Bl2 = (const bf16x8*)(l2wp + layer * 8192);
    const bf16x8* Blw = (const bf16x8*)(lwp + layer * 16384);
    const bf16x8* Bl1 = (const bf16x8*)l1wp_next;

    bf16x8 a0 = *(const bf16x8*)(&WR[lane * 8]);
    bf16x8 a1 = *(const bf16x8*)(&WR[512 + lane * 8]);
#pragma unroll
    for (int nt = 0; nt < 8; nt++) {
        float bias = l2b[layer * HCH + nt * 16 + col];
        floatx4 c = {bias, bias, bias, bias};
        c = MFMA(a0, Bl2[(nt * 2 + 0) * 64 + lane], c);
        c = MFMA(a1, Bl2[(nt * 2 + 1) * 64 + lane], c);
        int f = nt * 16 + col;
        int si0 = (f >> 5) * 512 + (16 * ((f >> 3) & 3)) * 8 + (f & 7);
#pragma unroll
        for (int reg = 0; reg < 4; reg++)
            WR[si0 + (quad * 4 + reg) * 8] = (short)f2bf(sspf(c[reg]));
    }
    bf16x8 af[4];
#pragma unroll
    for (int kk = 0; kk < 4; kk++)
        af[kk] = *(const bf16x8*)(&WR[kk * 512 + lane * 8]);
#pragma unroll
    for (int nt = 0; nt < 8; nt++) {
        float bias = lb[layer * HCH + nt * 16 + col];
        floatx4 c = {bias, bias, bias, bias};
#pragma unroll
        for (int kk = 0; kk < 4; kk++) c = MFMA(af[kk], Blw[(nt * 4 + kk) * 64 + lane], c);
        int f = nt * 16 + col;
        int si0 = (f >> 5) * 512 + (16 * ((f >> 3) & 3)) * 8 + (f & 7);
#pragma unroll
        for (int reg = 0; reg < 4; reg++) {
            int n = n0 + w * 16 + quad * 4 + reg;
            float hv = 0.f;
            if (n < N) {
                hv = h[(size_t)n * HCH + f] + c[reg];
                h[(size_t)n * HCH + f] = hv;
            }
            WR[si0 + (quad * 4 + reg) * 8] = (short)f2bf(hv);
        }
    }
#pragma unroll
    for (int kk = 0; kk < 4; kk++)
        af[kk] = *(const bf16x8*)(&WR[kk * 512 + lane * 8]);
#pragma unroll
    for (int nt = 0; nt < 4; nt++) {
        floatx4 c = {0.f, 0.f, 0.f, 0.f};
#pragma unroll
        for (int kk = 0; kk < 4; kk++) c = MFMA(af[kk], Bl1[(nt * 4 + kk) * 64 + lane], c);
        int f = nt * 16 + col;
#pragma unroll
        for (int reg = 0; reg < 4; reg++) {
            int n = n0 + w * 16 + quad * 4 + reg;
            if (n < N) xjb[(size_t)n * FCH + f] = f2bf(c[reg]);
        }
    }
}

// ---------------------------------------------------------------------------
// Final layer: node update + output MLP + segmented-shuffle readout.
// ---------------------------------------------------------------------------
__global__ __launch_bounds__(256) void k_final(
    const unsigned short* __restrict__ aggb, const short* __restrict__ l2wp,
    const float* __restrict__ l2b, const short* __restrict__ lwp,
    const float* __restrict__ lb,  const short* __restrict__ ow1p,
    const float* __restrict__ ob1, const float* __restrict__ ow2,
    const float* __restrict__ ob2, const int* __restrict__ batch,
    const float* __restrict__ h, float* __restrict__ out, int layer, int N)
{
    __shared__ __align__(16) short AR[8192];
    __shared__ float R[64 * 17];
    int t = threadIdx.x, lane = t & 63, w = t >> 6;
    int n0 = blockIdx.x * 64;
    short* WR = &AR[w * 2048];
#pragma unroll
    for (int m = 0; m < 8; m++) {
        int ii = lane + 64 * m;
        int rloc = ii >> 5;
        int k0 = (ii & 31) * 2;
        int n = n0 + w * 16 + rloc;
        unsigned pk = 0u;
        if (n < N) pk = *(const unsigned*)(&aggb[(size_t)n * FCH + k0]);
        int si = (k0 >> 5) * 512 + (rloc + 16 * ((k0 >> 3) & 3)) * 8 + (k0 & 7);
        *(unsigned*)(&WR[si]) = pk;
    }
    int quad = lane >> 4, col = lane & 15;
    const bf16x8* Bl2 = (const bf16x8*)(l2wp + layer * 8192);
    const bf16x8* Blw = (const bf16x8*)(lwp + layer * 16384);
    const bf16x8* Bow = (const bf16x8*)ow1p;

    bf16x8 a0 = *(const bf16x8*)(&WR[lane * 8]);
    bf16x8 a1 = *(const bf16x8*)(&WR[512 + lane * 8]);
#pragma unroll
    for (int nt = 0; nt < 8; nt++) {
        float bias = l2b[layer * HCH + nt * 16 + col];
        floatx4 c = {bias, bias, bias, bias};
        c = MFMA(a0, Bl2[(nt * 2 + 0) * 64 + lane], c);
        c = MFMA(a1, Bl2[(nt * 2 + 1) * 64 + lane], c);
        int f = nt * 16 + col;
        int si0 = (f >> 5) * 512 + (16 * ((f >> 3) & 3)) * 8 + (f & 7);
#pragma unroll
        for (int reg = 0; reg < 4; reg++)
            WR[si0 + (quad * 4 + reg) * 8] = (short)f2bf(sspf(c[reg]));
    }
    bf16x8 af[4];
#pragma unroll
    for (int kk = 0; kk < 4; kk++)
        af[kk] = *(const bf16x8*)(&WR[kk * 512 + lane * 8]);
#pragma unroll
    for (int nt = 0; nt < 8; nt++) {
        float bias = lb[layer * HCH + nt * 16 + col];
        floatx4 c = {bias, bias, bias, bias};
#pragma unroll
        for (int kk = 0; kk < 4; kk++) c = MFMA(af[kk], Blw[(nt * 4 + kk) * 64 + lane], c);
        int f = nt * 16 + col;
        int si0 = (f >> 5) * 512 + (16 * ((f >> 3) & 3)) * 8 + (f & 7);
#pragma unroll
        for (int reg = 0; reg < 4; reg++) {
            int n = n0 + w * 16 + quad * 4 + reg;
            float hv = 0.f;
            if (n < N) hv = h[(size_t)n * HCH + f] + c[reg];
            WR[si0 + (quad * 4 + reg) * 8] = (short)f2bf(hv);
        }
    }
#pragma unroll
    for (int kk = 0; kk < 4; kk++)
        af[kk] = *(const bf16x8*)(&WR[kk * 512 + lane * 8]);
    float p[4] = {0.f, 0.f, 0.f, 0.f};
#pragma unroll
    for (int nt = 0; nt < 4; nt++) {
        float bias = ob1[nt * 16 + col];
        floatx4 c = {bias, bias, bias, bias};
#pragma unroll
        for (int kk = 0; kk < 4; kk++) c = MFMA(af[kk], Bow[(nt * 4 + kk) * 64 + lane], c);
        float w2 = ow2[nt * 16 + col];
#pragma unroll
        for (int reg = 0; reg < 4; reg++) p[reg] += sspf(c[reg]) * w2;
    }
#pragma unroll
    for (int reg = 0; reg < 4; reg++)
        R[(w * 16 + quad * 4 + reg) * 17 + col] = p[reg];
    __syncthreads();
    if (t < 64) {
        int n = n0 + t;
        float v = 0.f;
        int g = -1;
        if (n < N) {
            v = ob2[0];
#pragma unroll
            for (int c2 = 0; c2 < 16; c2++) v += R[t * 17 + c2];
            g = batch[n];
        }
#pragma unroll
        for (int off2 = 1; off2 < 64; off2 <<= 1) {
            float vv = __shfl_down(v, off2, 64);
            int gg = __shfl_down(g, off2, 64);
            if (lane + off2 < 64 && gg == g) v += vv;
        }
        int gp = __shfl_up(g, 1, 64);
        bool head = (lane == 0) || (g != gp);
        if (head && g >= 0) unsafeAtomicAdd(&out[g], v);
    }
}

// ---------------------------------------------------------------------------
extern "C" void kernel_launch(void* const* d_in, const int* in_sizes, int n_in,
                              void* d_out, int out_size, void* d_ws, size_t ws_size,
                              hipStream_t stream)
{
    const int*   z    = (const int*)d_in[0];
    const float* pos  = (const float*)d_in[1];
    const int*   batc = (const int*)d_in[2];
    const int*   ei   = (const int*)d_in[3];
    const float* emb  = (const float*)d_in[4];
    const float* mw1  = (const float*)d_in[5];
    const float* mb1  = (const float*)d_in[6];
    const float* mw2  = (const float*)d_in[7];
    const float* mb2  = (const float*)d_in[8];
    const float* l1w  = (const float*)d_in[9];
    const float* l2w  = (const float*)d_in[10];
    const float* l2b  = (const float*)d_in[11];
    const float* lw   = (const float*)d_in[12];
    const float* lb   = (const float*)d_in[13];
    const float* ow1  = (const float*)d_in[14];
    const float* ob1  = (const float*)d_in[15];
    const float* ow2  = (const float*)d_in[16];
    const float* ob2  = (const float*)d_in[17];
    float* out = (float*)d_out;

    int N = in_sizes[0];
    int E = in_sizes[3] / 2;
    int nb2 = (N + 255) >> 8;        // coarse buckets (<=256 for N<=65536)

    char* ws = (char*)d_ws;
    size_t off = 0;
    auto alloc = [&](size_t bytes) {
        void* p = ws + off;
        off = (off + bytes + 255) & ~(size_t)255;
        return p;
    };
    float* h      = (float*)alloc((size_t)N * HCH * 4);
    unsigned short* xjb = (unsigned short*)alloc((size_t)N * FCH * 2);
    unsigned short* aggb = (unsigned short*)alloc((size_t)N * FCH * 2);
    int2*  ebuf   = (int2*)alloc((size_t)nb2 * CAP2 * 8);
    int2*  edata  = (int2*)alloc((size_t)E * 8);
    unsigned short* Wtab = (unsigned short*)alloc((size_t)LN * TBL * 64 * 2);
    int*   gcur   = (int*)alloc((size_t)nb2 * 64);      // 1 cursor / 64B line
    int*   rowptr = (int*)alloc(((size_t)nb2 * 256 + 1) * 4);
    short* l1wp   = (short*)alloc(LN * 8192 * 2);
    short* l2wp   = (short*)alloc(LN * 8192 * 2);
    short* lwp    = (short*)alloc(LN * 16384 * 2);
    short* ow1p   = (short*)alloc(8192 * 2);

    int NB = (N + 63) / 64;
    int NB4 = (N + 3) / 4;
    int S1B = (E + CHUNK - 1) / CHUNK;
    int PREB = LN * TBL + 32 + 1;

    k_pre<<<PREB, 64, 0, stream>>>(mw1, mb1, mw2, mb2, Wtab,
                                   l1w, l2w, lw, ow1, l1wp, l2wp, lwp, ow1p,
                                   gcur, out, nb2, out_size);
    k_s1<<<S1B, 256, 0, stream>>>(ei, pos, gcur, ebuf, E, nb2);
    k_s2n0<<<nb2 + NB, 512, 0, stream>>>(ebuf, gcur, edata, rowptr, nb2,
                                         z, emb, l1wp, h, xjb, N);
    for (int l = 0; l < LN; l++) {
        k_edge<<<NB4, 256, 0, stream>>>(rowptr, edata, xjb,
                                        Wtab + (size_t)l * TBL * 64, aggb, N);
        if (l < LN - 1) {
            k_update<<<NB, 256, 0, stream>>>(aggb, l2wp, l2b, lwp, lb,
                                             l1wp + (l + 1) * 8192, h, xjb, l, N);
        } else {
            k_final<<<NB, 256, 0, stream>>>(aggb, l2wp, l2b, lwp, lb, ow1p,
                                            ob1, ow2, ob2, batc, h, out, 2, N);
        }
    }
}

// Round 11
// 320.482 us; speedup vs baseline: 1.1024x; 1.0310x over previous
//
#include <hip/hip_runtime.h>

// ---------------------------------------------------------------------------
// SchNet-style GNN on MI355X — R27.
// R26 (330.4us, best). Remaining structure: k_edge x3 ~90us (L2/L3-gather +
// VALU floor), sort ~45us, MFMA kernels ~40us, gaps/fills. R27, three
// bit-identical reductions:
//  1) k_ps1: k_pre merged INTO k_s1's dispatch (s1 only needs gcur zeroed,
//     done by a 6KB memset). Wtab becomes 1 wave/(l,k) using shfl instead of
//     LDS broadcast -> merged kernel LDS = s1's 36.6KB only. Wtab's ~12us of
//     VALU hides under s1's latency phase.
//  2) edx: edata.y is dead after the sort (k_edge walks rowptr). k_s2 now
//     scatters 4B (src|tix) only: halves s2 scatter write + k_edge edge
//     stream (x3 layers).
//  3) 9 dispatches -> 8 (+1 tiny memset).
// ---------------------------------------------------------------------------

typedef short bf16x8 __attribute__((ext_vector_type(8)));
typedef unsigned short ushort8 __attribute__((ext_vector_type(8)));
typedef float floatx4 __attribute__((ext_vector_type(4)));

#define HCH 128
#define FCH 64
#define GCH 50
#define LN  3
#define TBL 4096
#define CAP2 12288       // slots per 256-node coarse bucket (mean 8192, sigma~90)
#define CHUNK 4096       // edges per k_s1 block (16/thread)
#define DMAX 8.6603f     // pos in [0,5)^3 -> d <= 5*sqrt(3)

#define MFMA(a, b, c) __builtin_amdgcn_mfma_f32_16x16x32_bf16((a), (b), (c), 0, 0, 0)

__device__ __forceinline__ unsigned short f2bf(float x) {
    unsigned int u = __float_as_uint(x);
    unsigned int r = (u + 0x7FFFu + ((u >> 16) & 1u)) >> 16;
    return (unsigned short)r;
}

__device__ __forceinline__ unsigned pk2bf(float lo, float hi) {
    unsigned ulo = __float_as_uint(lo) + 0x8000u;
    unsigned uhi = __float_as_uint(hi) + 0x8000u;
    return __builtin_amdgcn_perm(uhi, ulo, 0x07060302u);
}

__device__ __forceinline__ float bf2f(unsigned short u) {
    return __uint_as_float((unsigned)u << 16);
}

__device__ __forceinline__ float sspf(float x) {
    float t = __expf(-fabsf(x));
    float l = __logf(1.f + t);
    return fmaxf(x, 0.f) + l - 0.69314718056f;
}

__device__ __forceinline__ void fill_frag(const float* __restrict__ src,
                                          short* __restrict__ dst,
                                          int K, int F, int Ksrc,
                                          int tid, int nthr)
{
    int kc = K >> 5;
    int total = (F >> 4) * kc * 512;
    for (int i = tid; i < total; i += nthr) {
        int j = i & 7;
        int lane = (i >> 3) & 63;
        int rest = i >> 9;
        int kk = rest % kc;
        int nt = rest / kc;
        int k = kk * 32 + ((lane >> 4) << 3) + j;
        int f = nt * 16 + (lane & 15);
        float v = (k < Ksrc) ? src[k * F + f] : 0.f;
        dst[i] = (short)f2bf(v);
    }
}

// ---------------------------------------------------------------------------
// k_ps1: one dispatch for the whole prologue + stage-1 sort.
//   blocks [0, WTB)             : Wtab, 1 wave per (l,k), shfl broadcast
//   blocks [WTB, WTB+32)        : weight frag prep
//   block  WTB+32               : zero out
//   blocks [WTB+33, +S1B)       : stage-1 coarse-bucket sort
// gcur is zeroed by a prior hipMemsetAsync (s1's only prerequisite).
// ---------------------------------------------------------------------------
#define WTB (LN * TBL / 4)
__global__ __launch_bounds__(256) void k_ps1(
    const float* __restrict__ mw1, const float* __restrict__ mb1,
    const float* __restrict__ mw2, const float* __restrict__ mb2,
    unsigned short* __restrict__ Wtb,
    const float* __restrict__ l1w, const float* __restrict__ l2w,
    const float* __restrict__ lw,  const float* __restrict__ ow1,
    short* __restrict__ l1wp, short* __restrict__ l2wp,
    short* __restrict__ lwp,  short* __restrict__ ow1p,
    float* __restrict__ out, int osz,
    const int* __restrict__ ei, const float* __restrict__ pos,
    int* __restrict__ gcur, int2* __restrict__ ebuf, int E, int nb2)
{
    __shared__ int hist[256];
    __shared__ int lstart[256];
    __shared__ int lcur[256];
    __shared__ int gbase[256];
    __shared__ int wsum[4];
    __shared__ int2 stage[CHUNK];

    int blk = blockIdx.x;
    int t = threadIdx.x, lane = t & 63, w = t >> 6;

    if (blk < WTB) {
        // ---- Wtab: one wave per (l,k), sh[] replaced by shfl (bit-identical)
        int idx = blk * 4 + w;                 // [0, LN*TBL)
        int l = idx / TBL, k = idx - l * TBL;
        int f = lane;
        float d = (float)k * (DMAX / (float)(TBL - 1));
        const float step = 10.f / 49.f;
        const float coeff = -0.5f / (step * step);
        float t1 = mb1[l * 64 + f];
        const float* w1 = mw1 + l * GCH * 64;
        for (int g = 0; g < GCH; g++) {
            float u = d - (float)g * step;
            t1 += __expf(coeff * u * u) * w1[g * 64 + f];
        }
        float sv = sspf(t1);
        float acc = mb2[l * 64 + f];
        const float* w2 = mw2 + l * 64 * 64;
        for (int g = 0; g < 64; g++) acc += __shfl(sv, g, 64) * w2[g * 64 + f];
        float C = 0.5f * (__cosf(d * 0.31415926535897932f) + 1.f);
        Wtb[(size_t)idx * 64 + f] = f2bf(acc * C);
    } else if (blk < WTB + 32) {
        int tid = (blk - WTB) * 256 + t;
        int nthr = 32 * 256;
        for (int l = 0; l < LN; l++) {
            fill_frag(l1w + l * HCH * FCH, l1wp + l * 8192, 128, 64, 128, tid, nthr);
            fill_frag(l2w + l * FCH * HCH, l2wp + l * 8192, 64, 128, 64, tid, nthr);
            fill_frag(lw  + l * HCH * HCH, lwp  + l * 16384, 128, 128, 128, tid, nthr);
        }
        fill_frag(ow1, ow1p, 128, 64, 128, tid, nthr);
    } else if (blk == WTB + 32) {
        for (int i = t; i < osz; i += 256) out[i] = 0.f;
    } else {
        // ---- stage-1 coarse-bucket sort (R26 body, unchanged)
        int e0 = (blk - WTB - 33) * CHUNK;
        int e1 = min(e0 + CHUNK, E);
        int cnt = e1 - e0;

        hist[t] = 0;
        __syncthreads();

        int2 my[16];
        int  mybk[16];
#pragma unroll
        for (int i = 0; i < 16; i++) {
            int e = e0 + t + i * 256;
            int ec = min(e, E - 1);
            int s = ei[ec];
            int d2 = ei[E + ec];
            float dx = pos[s * 3 + 0] - pos[d2 * 3 + 0];
            float dy = pos[s * 3 + 1] - pos[d2 * 3 + 1];
            float dz = pos[s * 3 + 2] - pos[d2 * 3 + 2];
            float dist = sqrtf(dx * dx + dy * dy + dz * dz);
            int tix = (int)(dist * ((float)(TBL - 1) / DMAX) + 0.5f);
            tix = (tix > TBL - 1) ? (TBL - 1) : tix;
            my[i] = make_int2(s | (tix << 17), d2);
            mybk[i] = (e < e1) ? (d2 >> 8) : -1;
            if (mybk[i] >= 0) atomicAdd(&hist[mybk[i]], 1);
        }
        __syncthreads();

        int base0;
        {
            int c = hist[t];
            int a = c;
#pragma unroll
            for (int o = 1; o < 64; o <<= 1) {
                int u = __shfl_up(a, o, 64);
                if (lane >= o) a += u;
            }
            if (lane == 63) wsum[w] = a;
            __syncthreads();
            int prefix = 0;
#pragma unroll
            for (int i = 0; i < 4; i++) if (i < w) prefix += wsum[i];
            int ls = prefix + a - c;
            lstart[t] = ls; lcur[t] = ls;
            base0 = (c && t < nb2) ? atomicAdd(&gcur[t * 16], c) : 0;
        }
        __syncthreads();

#pragma unroll
        for (int i = 0; i < 16; i++) {
            if (mybk[i] >= 0) {
                int ofs = atomicAdd(&lcur[mybk[i]], 1);
                stage[ofs] = my[i];
            }
        }
        gbase[t] = t * CAP2 + base0;
        __syncthreads();

        for (int i = t; i < cnt; i += 256) {
            int2 ed = stage[i];
            int bk = ed.y >> 8;
            int g = gbase[bk] + (i - lstart[bk]);
            if (g < bk * CAP2 + CAP2) ebuf[g] = ed;
        }
    }
}

// ---------------------------------------------------------------------------
// k_s2n0: one dispatch. blocks [0,nb2): per-bucket counting sort -> edx
// (src|tix only; dst is dead after sorting) + rowptr; blocks [nb2, nb2+NB):
// node0 (h = emb[z]; xjb = h @ l1w[0]) on t<256.
// ---------------------------------------------------------------------------
__global__ __launch_bounds__(512) void k_s2n0(
    const int2* __restrict__ ebuf, const int* __restrict__ gcur,
    int* __restrict__ edx, int* __restrict__ rowptr, int nb2,
    const int* __restrict__ z, const float* __restrict__ emb,
    const short* __restrict__ l1wp0, float* __restrict__ h,
    unsigned short* __restrict__ xjb, int N)
{
    __shared__ int hist[256];
    __shared__ int bcur[256];
    __shared__ int wred[8];
    __shared__ __align__(16) short A3[8192];
    __shared__ int zL[64];
    int t = threadIdx.x, lane = t & 63, w = t >> 6;
    int bk = blockIdx.x;
    if (bk < nb2) {
        int cnt = min(gcur[bk * 16], CAP2);
        int v = (t < bk && t < nb2) ? min(gcur[t * 16], CAP2) : 0;
#pragma unroll
        for (int o = 32; o; o >>= 1) v += __shfl_down(v, o, 64);
        if (lane == 0) wred[w] = v;
        if (t < 256) hist[t] = 0;
        __syncthreads();
        int gs = 0;
#pragma unroll
        for (int i = 0; i < 8; i++) gs += wred[i];

        const int2* eb = ebuf + (size_t)bk * CAP2;
        for (int i = t; i < cnt; i += 512)
            atomicAdd(&hist[eb[i].y & 255], 1);
        __syncthreads();
        int myc = (t < 256) ? hist[t] : 0;
        for (int o = 1; o < 256; o <<= 1) {
            int u = (t < 256 && t >= o) ? hist[t - o] : 0;
            __syncthreads();
            if (t < 256) hist[t] += u;
            __syncthreads();
        }
        if (t < 256) {
            int start = gs + hist[t] - myc;
            bcur[t] = start;
            rowptr[(bk << 8) + t] = start;
        }
        if (bk == nb2 - 1 && t == 0) rowptr[nb2 << 8] = gs + cnt;
        __syncthreads();
        for (int i = t; i < cnt; i += 512) {
            int2 ed = eb[i];
            int dl = ed.y & 255;
            int p = atomicAdd(&bcur[dl], 1);
            edx[p] = ed.x;
        }
    } else {
        int n0 = (bk - nb2) * 64;
        if (t < 64) { int n = n0 + t; zL[t] = (n < N) ? z[n] : 0; }
        __syncthreads();
        if (t < 256) {
#pragma unroll
            for (int m = 0; m < 16; m++) {
                int ii = lane + 64 * m;
                int rloc = ii >> 6;
                int k0 = (ii & 63) * 2;
                int n = n0 + w * 16 + rloc;
                float2 v = make_float2(0.f, 0.f);
                if (n < N) {
                    v = *(const float2*)(&emb[(size_t)zL[w * 16 + rloc] * HCH + k0]);
                    *(float2*)(&h[(size_t)n * HCH + k0]) = v;
                }
                unsigned pk = pk2bf(v.x, v.y);
                int si = w * 2048 + (k0 >> 5) * 512 + (rloc + 16 * ((k0 >> 3) & 3)) * 8 + (k0 & 7);
                *(unsigned*)(&A3[si]) = pk;
            }
            int quad = lane >> 4, col = lane & 15;
            const bf16x8* B = (const bf16x8*)l1wp0;
            bf16x8 af[4];
#pragma unroll
            for (int kk = 0; kk < 4; kk++)
                af[kk] = *(const bf16x8*)(&A3[w * 2048 + kk * 512 + lane * 8]);
#pragma unroll
            for (int nt = 0; nt < 4; nt++) {
                floatx4 c = {0.f, 0.f, 0.f, 0.f};
#pragma unroll
                for (int kk = 0; kk < 4; kk++) c = MFMA(af[kk], B[(nt * 4 + kk) * 64 + lane], c);
                int f = nt * 16 + col;
#pragma unroll
                for (int reg = 0; reg < 4; reg++) {
                    int n = n0 + w * 16 + quad * 4 + reg;
                    if (n < N) xjb[(size_t)n * FCH + f] = f2bf(c[reg]);
                }
            }
        }
    }
}

// ---------------------------------------------------------------------------
// Edge kernel (R24 structure, edx stream): one WAVE per dst node, 8-channel
// lanes via uint4. slot = lane>>3 handles 2 edges of each 16-edge batch;
// lane&7 owns an 8-channel group. Output: bf16 agg row. Zero atomics/LDS.
// ---------------------------------------------------------------------------
__global__ __launch_bounds__(256) void k_edge(
    const int* __restrict__ rowptr, const int* __restrict__ edx,
    const unsigned short* __restrict__ xjb, const unsigned short* __restrict__ Wt,
    unsigned short* __restrict__ aggb, int N)
{
    int t = threadIdx.x, lane = t & 63, w = t >> 6;
    int n = blockIdx.x * 4 + w;
    if (n >= N) return;
    int beg = rowptr[n];
    int end = rowptr[n + 1];
    int slot = lane >> 3;            // 0..7: edge pair within the 16-edge batch
    int cq = (lane & 7) * 8;         // 8-channel base
    const unsigned short* xp = xjb + cq;
    const unsigned short* wp = Wt + cq;
    float acc[8];
#pragma unroll
    for (int j = 0; j < 8; j++) acc[j] = 0.f;
    for (int e = beg; e < end; e += 16) {
        int eb = e + slot * 2;
        int exv[2];
        exv[0] = edx[min(eb + 0, end - 1)];
        exv[1] = edx[min(eb + 1, end - 1)];
        uint4 xq[2], wq[2];
#pragma unroll
        for (int i = 0; i < 2; i++) {
            int s   = exv[i] & 0x1FFFF;
            int tix = (int)(((unsigned)exv[i]) >> 17);
            xq[i] = *(const uint4*)(xp + ((size_t)s << 6));
            wq[i] = *(const uint4*)(wp + ((size_t)tix << 6));
        }
#pragma unroll
        for (int i = 0; i < 2; i++) {
            if (eb + i >= end) { wq[i].x = 0u; wq[i].y = 0u; wq[i].z = 0u; wq[i].w = 0u; }
            acc[0] += __uint_as_float(xq[i].x << 16)         * __uint_as_float(wq[i].x << 16);
            acc[1] += __uint_as_float(xq[i].x & 0xFFFF0000u) * __uint_as_float(wq[i].x & 0xFFFF0000u);
            acc[2] += __uint_as_float(xq[i].y << 16)         * __uint_as_float(wq[i].y << 16);
            acc[3] += __uint_as_float(xq[i].y & 0xFFFF0000u) * __uint_as_float(wq[i].y & 0xFFFF0000u);
            acc[4] += __uint_as_float(xq[i].z << 16)         * __uint_as_float(wq[i].z << 16);
            acc[5] += __uint_as_float(xq[i].z & 0xFFFF0000u) * __uint_as_float(wq[i].z & 0xFFFF0000u);
            acc[6] += __uint_as_float(xq[i].w << 16)         * __uint_as_float(wq[i].w << 16);
            acc[7] += __uint_as_float(xq[i].w & 0xFFFF0000u) * __uint_as_float(wq[i].w & 0xFFFF0000u);
        }
    }
#pragma unroll
    for (int o = 8; o < 64; o <<= 1) {
#pragma unroll
        for (int j = 0; j < 8; j++) acc[j] += __shfl_xor(acc[j], o, 64);
    }
    if (slot == 0) {
        uint4 pk;
        pk.x = pk2bf(acc[0], acc[1]);
        pk.y = pk2bf(acc[2], acc[3]);
        pk.z = pk2bf(acc[4], acc[5]);
        pk.w = pk2bf(acc[6], acc[7]);
        *(uint4*)(aggb + (size_t)n * FCH + cq) = pk;
    }
}

// ---------------------------------------------------------------------------
// Node update (layers 0,1): single LDS arena; agg arrives pre-packed bf16.
// ---------------------------------------------------------------------------
__global__ __launch_bounds__(256) void k_update(
    const unsigned short* __restrict__ aggb, const short* __restrict__ l2wp,
    const float* __restrict__ l2b, const short* __restrict__ lwp,
    const float* __restrict__ lb,  const short* __restrict__ l1wp_next,
    float* __restrict__ h, unsigned short* __restrict__ xjb, int layer, int N)
{
    __shared__ __align__(16) short AR[8192];
    int t = threadIdx.x, lane = t & 63, w = t >> 6;
    int n0 = blockIdx.x * 64;
    short* WR = &AR[w * 2048];
#pragma unroll
    for (int m = 0; m < 8; m++) {
        int ii = lane + 64 * m;
        int rloc = ii >> 5;
        int k0 = (ii & 31) * 2;
        int n = n0 + w * 16 + rloc;
        unsigned pk = 0u;
        if (n < N) pk = *(const unsigned*)(&aggb[(size_t)n * FCH + k0]);
        int si = (k0 >> 5) * 512 + (rloc + 16 * ((k0 >> 3) & 3)) * 8 + (k0 & 7);
        *(unsigned*)(&WR[si]) = pk;
    }
    int quad = lane >> 4, col = lane & 15;
    const bf16x8* Bl2 = (const bf16x8*)(l2wp + layer * 8192);
    const bf16x8* Blw = (const bf16x8*)(lwp + layer * 16384);
    const bf16x8* Bl1 = (const bf16x8*)l1wp_next;

    bf16x8 a0 = *(const bf16x8*)(&WR[lane * 8]);
    bf16x8 a1 = *(const bf16x8*)(&WR[512 + lane * 8]);
#pragma unroll
    for (int nt = 0; nt < 8; nt++) {
        float bias = l2b[layer * HCH + nt * 16 + col];
        floatx4 c = {bias, bias, bias, bias};
        c = MFMA(a0, Bl2[(nt * 2 + 0) * 64 + lane], c);
        c = MFMA(a1, Bl2[(nt * 2 + 1) * 64 + lane], c);
        int f = nt * 16 + col;
        int si0 = (f >> 5) * 512 + (16 * ((f >> 3) & 3)) * 8 + (f & 7);
#pragma unroll
        for (int reg = 0; reg < 4; reg++)
            WR[si0 + (quad * 4 + reg) * 8] = (short)f2bf(sspf(c[reg]));
    }
    bf16x8 af[4];
#pragma unroll
    for (int kk = 0; kk < 4; kk++)
        af[kk] = *(const bf16x8*)(&WR[kk * 512 + lane * 8]);
#pragma unroll
    for (int nt = 0; nt < 8; nt++) {
        float bias = lb[layer * HCH + nt * 16 + col];
        floatx4 c = {bias, bias, bias, bias};
#pragma unroll
        for (int kk = 0; kk < 4; kk++) c = MFMA(af[kk], Blw[(nt * 4 + kk) * 64 + lane], c);
        int f = nt * 16 + col;
        int si0 = (f >> 5) * 512 + (16 * ((f >> 3) & 3)) * 8 + (f & 7);
#pragma unroll
        for (int reg = 0; reg < 4; reg++) {
            int n = n0 + w * 16 + quad * 4 + reg;
            float hv = 0.f;
            if (n < N) {
                hv = h[(size_t)n * HCH + f] + c[reg];
                h[(size_t)n * HCH + f] = hv;
            }
            WR[si0 + (quad * 4 + reg) * 8] = (short)f2bf(hv);
        }
    }
#pragma unroll
    for (int kk = 0; kk < 4; kk++)
        af[kk] = *(const bf16x8*)(&WR[kk * 512 + lane * 8]);
#pragma unroll
    for (int nt = 0; nt < 4; nt++) {
        floatx4 c = {0.f, 0.f, 0.f, 0.f};
#pragma unroll
        for (int kk = 0; kk < 4; kk++) c = MFMA(af[kk], Bl1[(nt * 4 + kk) * 64 + lane], c);
        int f = nt * 16 + col;
#pragma unroll
        for (int reg = 0; reg < 4; reg++) {
            int n = n0 + w * 16 + quad * 4 + reg;
            if (n < N) xjb[(size_t)n * FCH + f] = f2bf(c[reg]);
        }
    }
}

// ---------------------------------------------------------------------------
// Final layer: node update + output MLP + segmented-shuffle readout.
// ---------------------------------------------------------------------------
__global__ __launch_bounds__(256) void k_final(
    const unsigned short* __restrict__ aggb, const short* __restrict__ l2wp,
    const float* __restrict__ l2b, const short* __restrict__ lwp,
    const float* __restrict__ lb,  const short* __restrict__ ow1p,
    const float* __restrict__ ob1, const float* __restrict__ ow2,
    const float* __restrict__ ob2, const int* __restrict__ batch,
    const float* __restrict__ h, float* __restrict__ out, int layer, int N)
{
    __shared__ __align__(16) short AR[8192];
    __shared__ float R[64 * 17];
    int t = threadIdx.x, lane = t & 63, w = t >> 6;
    int n0 = blockIdx.x * 64;
    short* WR = &AR[w * 2048];
#pragma unroll
    for (int m = 0; m < 8; m++) {
        int ii = lane + 64 * m;
        int rloc = ii >> 5;
        int k0 = (ii & 31) * 2;
        int n = n0 + w * 16 + rloc;
        unsigned pk = 0u;
        if (n < N) pk = *(const unsigned*)(&aggb[(size_t)n * FCH + k0]);
        int si = (k0 >> 5) * 512 + (rloc + 16 * ((k0 >> 3) & 3)) * 8 + (k0 & 7);
        *(unsigned*)(&WR[si]) = pk;
    }
    int quad = lane >> 4, col = lane & 15;
    const bf16x8* Bl2 = (const bf16x8*)(l2wp + layer * 8192);
    const bf16x8* Blw = (const bf16x8*)(lwp + layer * 16384);
    const bf16x8* Bow = (const bf16x8*)ow1p;

    bf16x8 a0 = *(const bf16x8*)(&WR[lane * 8]);
    bf16x8 a1 = *(const bf16x8*)(&WR[512 + lane * 8]);
#pragma unroll
    for (int nt = 0; nt < 8; nt++) {
        float bias = l2b[layer * HCH + nt * 16 + col];
        floatx4 c = {bias, bias, bias, bias};
        c = MFMA(a0, Bl2[(nt * 2 + 0) * 64 + lane], c);
        c = MFMA(a1, Bl2[(nt * 2 + 1) * 64 + lane], c);
        int f = nt * 16 + col;
        int si0 = (f >> 5) * 512 + (16 * ((f >> 3) & 3)) * 8 + (f & 7);
#pragma unroll
        for (int reg = 0; reg < 4; reg++)
            WR[si0 + (quad * 4 + reg) * 8] = (short)f2bf(sspf(c[reg]));
    }
    bf16x8 af[4];
#pragma unroll
    for (int kk = 0; kk < 4; kk++)
        af[kk] = *(const bf16x8*)(&WR[kk * 512 + lane * 8]);
#pragma unroll
    for (int nt = 0; nt < 8; nt++) {
        float bias = lb[layer * HCH + nt * 16 + col];
        floatx4 c = {bias, bias, bias, bias};
#pragma unroll
        for (int kk = 0; kk < 4; kk++) c = MFMA(af[kk], Blw[(nt * 4 + kk) * 64 + lane], c);
        int f = nt * 16 + col;
        int si0 = (f >> 5) * 512 + (16 * ((f >> 3) & 3)) * 8 + (f & 7);
#pragma unroll
        for (int reg = 0; reg < 4; reg++) {
            int n = n0 + w * 16 + quad * 4 + reg;
            float hv = 0.f;
            if (n < N) hv = h[(size_t)n * HCH + f] + c[reg];
            WR[si0 + (quad * 4 + reg) * 8] = (short)f2bf(hv);
        }
    }
#pragma unroll
    for (int kk = 0; kk < 4; kk++)
        af[kk] = *(const bf16x8*)(&WR[kk * 512 + lane * 8]);
    float p[4] = {0.f, 0.f, 0.f, 0.f};
#pragma unroll
    for (int nt = 0; nt < 4; nt++) {
        float bias = ob1[nt * 16 + col];
        floatx4 c = {bias, bias, bias, bias};
#pragma unroll
        for (int kk = 0; kk < 4; kk++) c = MFMA(af[kk], Bow[(nt * 4 + kk) * 64 + lane], c);
        float w2 = ow2[nt * 16 + col];
#pragma unroll
        for (int reg = 0; reg < 4; reg++) p[reg] += sspf(c[reg]) * w2;
    }
#pragma unroll
    for (int reg = 0; reg < 4; reg++)
        R[(w * 16 + quad * 4 + reg) * 17 + col] = p[reg];
    __syncthreads();
    if (t < 64) {
        int n = n0 + t;
        float v = 0.f;
        int g = -1;
        if (n < N) {
            v = ob2[0];
#pragma unroll
            for (int c2 = 0; c2 < 16; c2++) v += R[t * 17 + c2];
            g = batch[n];
        }
#pragma unroll
        for (int off2 = 1; off2 < 64; off2 <<= 1) {
            float vv = __shfl_down(v, off2, 64);
            int gg = __shfl_down(g, off2, 64);
            if (lane + off2 < 64 && gg == g) v += vv;
        }
        int gp = __shfl_up(g, 1, 64);
        bool head = (lane == 0) || (g != gp);
        if (head && g >= 0) unsafeAtomicAdd(&out[g], v);
    }
}

// ---------------------------------------------------------------------------
extern "C" void kernel_launch(void* const* d_in, const int* in_sizes, int n_in,
                              void* d_out, int out_size, void* d_ws, size_t ws_size,
                              hipStream_t stream)
{
    const int*   z    = (const int*)d_in[0];
    const float* pos  = (const float*)d_in[1];
    const int*   batc = (const int*)d_in[2];
    const int*   ei   = (const int*)d_in[3];
    const float* emb  = (const float*)d_in[4];
    const float* mw1  = (const float*)d_in[5];
    const float* mb1  = (const float*)d_in[6];
    const float* mw2  = (const float*)d_in[7];
    const float* mb2  = (const float*)d_in[8];
    const float* l1w  = (const float*)d_in[9];
    const float* l2w  = (const float*)d_in[10];
    const float* l2b  = (const float*)d_in[11];
    const float* lw   = (const float*)d_in[12];
    const float* lb   = (const float*)d_in[13];
    const float* ow1  = (const float*)d_in[14];
    const float* ob1  = (const float*)d_in[15];
    const float* ow2  = (const float*)d_in[16];
    const float* ob2  = (const float*)d_in[17];
    float* out = (float*)d_out;

    int N = in_sizes[0];
    int E = in_sizes[3] / 2;
    int nb2 = (N + 255) >> 8;        // coarse buckets (<=256 for N<=65536)

    char* ws = (char*)d_ws;
    size_t off = 0;
    auto alloc = [&](size_t bytes) {
        void* p = ws + off;
        off = (off + bytes + 255) & ~(size_t)255;
        return p;
    };
    float* h      = (float*)alloc((size_t)N * HCH * 4);
    unsigned short* xjb = (unsigned short*)alloc((size_t)N * FCH * 2);
    unsigned short* aggb = (unsigned short*)alloc((size_t)N * FCH * 2);
    int2*  ebuf   = (int2*)alloc((size_t)nb2 * CAP2 * 8);
    int*   edx    = (int*)alloc((size_t)E * 4);
    unsigned short* Wtab = (unsigned short*)alloc((size_t)LN * TBL * 64 * 2);
    int*   gcur   = (int*)alloc((size_t)nb2 * 64);      // 1 cursor / 64B line
    int*   rowptr = (int*)alloc(((size_t)nb2 * 256 + 1) * 4);
    short* l1wp   = (short*)alloc(LN * 8192 * 2);
    short* l2wp   = (short*)alloc(LN * 8192 * 2);
    short* lwp    = (short*)alloc(LN * 16384 * 2);
    short* ow1p   = (short*)alloc(8192 * 2);

    int NB = (N + 63) / 64;
    int NB4 = (N + 3) / 4;
    int S1B = (E + CHUNK - 1) / CHUNK;
    int PS1B = WTB + 32 + 1 + S1B;

    hipMemsetAsync(gcur, 0, (size_t)nb2 * 64, stream);
    k_ps1<<<PS1B, 256, 0, stream>>>(mw1, mb1, mw2, mb2, Wtab,
                                    l1w, l2w, lw, ow1, l1wp, l2wp, lwp, ow1p,
                                    out, out_size,
                                    ei, pos, gcur, ebuf, E, nb2);
    k_s2n0<<<nb2 + NB, 512, 0, stream>>>(ebuf, gcur, edx, rowptr, nb2,
                                         z, emb, l1wp, h, xjb, N);
    for (int l = 0; l < LN; l++) {
        k_edge<<<NB4, 256, 0, stream>>>(rowptr, edx, xjb,
                                        Wtab + (size_t)l * TBL * 64, aggb, N);
        if (l < LN - 1) {
            k_update<<<NB, 256, 0, stream>>>(aggb, l2wp, l2b, lwp, lb,
                                             l1wp + (l + 1) * 8192, h, xjb, l, N);
        } else {
            k_final<<<NB, 256, 0, stream>>>(aggb, l2wp, l2b, lwp, lb, ow1p,
                                            ob1, ow2, ob2, batc, h, out, 2, N);
        }
    }
}